// Round 3
// baseline (240.959 us; speedup 1.0000x reference)
//
#include <hip/hip_runtime.h>
#include <hip/hip_bf16.h>
#include <cmath>

#define NN 8192
#define FIN 256
#define FOUT 128
#define IBLK 128      // i-rows per pass_b block (4 waves x 32)
#define JW 256        // mask-window width (ballot granularity)
#define JT 64         // LDS tile step width
#define LDSPITCH 144  // 128B data + 16B pad per row -> conflict-free

typedef short short8 __attribute__((ext_vector_type(8)));
typedef float f32x16 __attribute__((ext_vector_type(16)));

static __device__ __forceinline__ unsigned short f2bf(float f) {
    unsigned u = __float_as_uint(f);
    u += 0x7fffu + ((u >> 16) & 1u);
    return (unsigned short)(u >> 16);
}

// ---------------------------------------------------------------------------
// Pass A: h = input @ W^T + Wb (bf16 MFMA, h^T form). Writes hT2 in j-tiled
// layout [j>>6][FOUT][j&63] (so pass_b tiles are contiguous 16KB), plus
// s[i] = h[i]·a1, t[j] = h[j]·a2 + ab.
// ---------------------------------------------------------------------------
__global__ __launch_bounds__(256, 2)
void gat_pass_a(const float* __restrict__ input, const float* __restrict__ W,
                const float* __restrict__ Wb, const float* __restrict__ aw,
                const float* __restrict__ ab, unsigned short* __restrict__ hT2,
                float* __restrict__ s_out, float* __restrict__ t_out) {
    const int tid = threadIdx.x;
    const int w = tid >> 6, l = tid & 63;
    const int l5 = l >> 5, l31 = l & 31;
    const int nt = w >> 1, mh = w & 1;
    const int bx = blockIdx.x;
    const int i = bx * 64 + nt * 32 + l31;

    f32x16 acc0 = {}; f32x16 acc1 = {};
    #pragma unroll
    for (int ks = 0; ks < FIN / 16; ++ks) {
        const int c0 = ks * 16 + l5 * 8;
        const float4 b0 = *(const float4*)(input + (size_t)i * FIN + c0);
        const float4 b1 = *(const float4*)(input + (size_t)i * FIN + c0 + 4);
        short8 bf;
        bf[0]=(short)f2bf(b0.x); bf[1]=(short)f2bf(b0.y); bf[2]=(short)f2bf(b0.z); bf[3]=(short)f2bf(b0.w);
        bf[4]=(short)f2bf(b1.x); bf[5]=(short)f2bf(b1.y); bf[6]=(short)f2bf(b1.z); bf[7]=(short)f2bf(b1.w);
        {
            const int kcol = l31 + 32 * (2 * mh + 0);
            const float4 a0 = *(const float4*)(W + (size_t)kcol * FIN + c0);
            const float4 a1 = *(const float4*)(W + (size_t)kcol * FIN + c0 + 4);
            short8 af;
            af[0]=(short)f2bf(a0.x); af[1]=(short)f2bf(a0.y); af[2]=(short)f2bf(a0.z); af[3]=(short)f2bf(a0.w);
            af[4]=(short)f2bf(a1.x); af[5]=(short)f2bf(a1.y); af[6]=(short)f2bf(a1.z); af[7]=(short)f2bf(a1.w);
            acc0 = __builtin_amdgcn_mfma_f32_32x32x16_bf16(af, bf, acc0, 0, 0, 0);
        }
        {
            const int kcol = l31 + 32 * (2 * mh + 1);
            const float4 a0 = *(const float4*)(W + (size_t)kcol * FIN + c0);
            const float4 a1 = *(const float4*)(W + (size_t)kcol * FIN + c0 + 4);
            short8 af;
            af[0]=(short)f2bf(a0.x); af[1]=(short)f2bf(a0.y); af[2]=(short)f2bf(a0.z); af[3]=(short)f2bf(a0.w);
            af[4]=(short)f2bf(a1.x); af[5]=(short)f2bf(a1.y); af[6]=(short)f2bf(a1.z); af[7]=(short)f2bf(a1.w);
            acc1 = __builtin_amdgcn_mfma_f32_32x32x16_bf16(af, bf, acc1, 0, 0, 0);
        }
    }
    __shared__ float sred[4][32];
    __shared__ float tred[4][32];
    float sacc = 0.f, tacc = 0.f;
    #pragma unroll
    for (int m = 0; m < 2; ++m) {
        #pragma unroll
        for (int r = 0; r < 16; ++r) {
            const int kcol = 32 * (2 * mh + m) + 4 * l5 + (r & 3) + 8 * (r >> 2);
            const float hv = (m ? acc1[r] : acc0[r]) + Wb[kcol];
            // j-tiled layout: element (kcol, j=i) at [(i>>6)*FOUT + kcol]*64 + (i&63)
            hT2[((size_t)bx * FOUT + kcol) * 64 + (nt * 32 + l31)] = f2bf(hv);
            sacc += hv * aw[kcol];
            tacc += hv * aw[FOUT + kcol];
        }
    }
    sacc += __shfl_xor(sacc, 32);
    tacc += __shfl_xor(tacc, 32);
    if (l < 32) { sred[w][l] = sacc; tred[w][l] = tacc; }
    __syncthreads();
    if (mh == 0 && l < 32) {
        s_out[i] = sred[w][l] + sred[w + 1][l];
        t_out[i] = tred[w][l] + tred[w + 1][l] + ab[0];
    }
}

// ---------------------------------------------------------------------------
// Pass B (fused): streams adj directly (1KB-contiguous int4 + __ballot),
// LDS-staged hT2 tiles (padded rows, conflict-free), in-register P build,
// 32x32x16 MFMA. Writes transposed partials numw[chunk][FOUT][NN], dpart.
// 4 waves/block, each wave owns 32 i-rows x all 128 kcols.
// ---------------------------------------------------------------------------
__global__ __launch_bounds__(256, 2)
void gat_pass_b(const int* __restrict__ adj, const unsigned short* __restrict__ hT2,
                const float* __restrict__ s_in, const float* __restrict__ t_in,
                float* __restrict__ numw, float* __restrict__ dpart, int jc) {
    __shared__ int4 lds4[IBLK * LDSPITCH / 16];
    char* lds = (char*)lds4;

    const int tid = threadIdx.x;
    const int w = tid >> 6, l = tid & 63;
    const int l5 = l >> 5, l31 = l & 31;
    const int iw0 = blockIdx.x * IBLK + w * 32;
    const int chunk = blockIdx.y;
    const int jb = chunk * jc;
    const float si = s_in[iw0 + l31];

    f32x16 acc0 = {}, acc1 = {}, acc2 = {}, acc3 = {};
    float dacc = 0.f;

    // staging registers: R[q] holds 16B of the next tile.
    // global mapping: instr q covers contiguous 1KB: byte G = w*4096 + q*1024 + l*16
    // -> LDS row r = G>>7 = w*32 + q*8 + (l>>3), y = (l&7)*16
    int4 R0, R1, R2, R3;
    const char* gt = (const char*)hT2;
    const size_t gl = (size_t)w * 4096 + (size_t)l * 16;
    {
        const char* gp = gt + (size_t)(jb >> 6) * FOUT * 128 + gl;
        R0 = *(const int4*)(gp);
        R1 = *(const int4*)(gp + 1024);
        R2 = *(const int4*)(gp + 2048);
        R3 = *(const int4*)(gp + 3072);
    }
    const int ldsrow0 = (w * 32 + (l >> 3)) * LDSPITCH + (l & 7) * 16;

    const int nw = jc / JW;
    for (int s4 = 0; s4 < nw; ++s4) {
        const int jw0 = jb + s4 * JW;
        // ---- build masks for this 256-j window via ballot ----
        unsigned long long m0 = 0, m1 = 0, m2 = 0, m3 = 0;
        const int* abase = adj + (size_t)iw0 * NN + jw0;
        #pragma unroll 8
        for (int r = 0; r < 32; ++r) {
            const int4 a4 = *(const int4*)(abase + (size_t)r * NN + l * 4);
            const unsigned long long b0 = __ballot(a4.x > 0);
            const unsigned long long b1 = __ballot(a4.y > 0);
            const unsigned long long b2 = __ballot(a4.z > 0);
            const unsigned long long b3 = __ballot(a4.w > 0);
            if (l31 == r) { m0 = b0; m1 = b1; m2 = b2; m3 = b3; }
        }
        // ---- 4 tile steps of 64 j ----
        #pragma unroll
        for (int ss = 0; ss < JW / JT; ++ss) {
            const int j0 = jw0 + ss * JT;
            __syncthreads();   // all waves done reading previous tile
            *(int4*)(lds + ldsrow0)                 = R0;
            *(int4*)(lds + ldsrow0 + 8 * LDSPITCH)  = R1;
            *(int4*)(lds + ldsrow0 + 16 * LDSPITCH) = R2;
            *(int4*)(lds + ldsrow0 + 24 * LDSPITCH) = R3;
            if (!(s4 == nw - 1 && ss == JW / JT - 1)) {
                const char* gp = gt + (size_t)((j0 + JT) >> 6) * FOUT * 128 + gl;
                R0 = *(const int4*)(gp);
                R1 = *(const int4*)(gp + 1024);
                R2 = *(const int4*)(gp + 2048);
                R3 = *(const int4*)(gp + 3072);
            }
            __syncthreads();   // tile ready

            #pragma unroll
            for (int kg = 0; kg < 4; ++kg) {
                const int bb = ss * 16 + kg * 4 + l5 * 2;
                const float4 t0 = *(const float4*)(t_in + j0 + kg * 16 + l5 * 8);
                const float4 t1 = *(const float4*)(t_in + j0 + kg * 16 + l5 * 8 + 4);
                short8 bf;
                float x, p;
                x = si + t0.x; x = fmaxf(x, 0.2f * x); p = __expf(x);
                p = ((m0 >> bb) & 1ull) ? p : 0.f; dacc += p; bf[0] = (short)f2bf(p);
                x = si + t0.y; x = fmaxf(x, 0.2f * x); p = __expf(x);
                p = ((m1 >> bb) & 1ull) ? p : 0.f; dacc += p; bf[1] = (short)f2bf(p);
                x = si + t0.z; x = fmaxf(x, 0.2f * x); p = __expf(x);
                p = ((m2 >> bb) & 1ull) ? p : 0.f; dacc += p; bf[2] = (short)f2bf(p);
                x = si + t0.w; x = fmaxf(x, 0.2f * x); p = __expf(x);
                p = ((m3 >> bb) & 1ull) ? p : 0.f; dacc += p; bf[3] = (short)f2bf(p);
                x = si + t1.x; x = fmaxf(x, 0.2f * x); p = __expf(x);
                p = ((m0 >> (bb + 1)) & 1ull) ? p : 0.f; dacc += p; bf[4] = (short)f2bf(p);
                x = si + t1.y; x = fmaxf(x, 0.2f * x); p = __expf(x);
                p = ((m1 >> (bb + 1)) & 1ull) ? p : 0.f; dacc += p; bf[5] = (short)f2bf(p);
                x = si + t1.z; x = fmaxf(x, 0.2f * x); p = __expf(x);
                p = ((m2 >> (bb + 1)) & 1ull) ? p : 0.f; dacc += p; bf[6] = (short)f2bf(p);
                x = si + t1.w; x = fmaxf(x, 0.2f * x); p = __expf(x);
                p = ((m3 >> (bb + 1)) & 1ull) ? p : 0.f; dacc += p; bf[7] = (short)f2bf(p);

                const int fb = kg * 32 + l5 * 16;
                const short8 af0 = *(const short8*)(lds + (0 * 32 + l31) * LDSPITCH + fb);
                const short8 af1 = *(const short8*)(lds + (1 * 32 + l31) * LDSPITCH + fb);
                const short8 af2 = *(const short8*)(lds + (2 * 32 + l31) * LDSPITCH + fb);
                const short8 af3 = *(const short8*)(lds + (3 * 32 + l31) * LDSPITCH + fb);
                acc0 = __builtin_amdgcn_mfma_f32_32x32x16_bf16(af0, bf, acc0, 0, 0, 0);
                acc1 = __builtin_amdgcn_mfma_f32_32x32x16_bf16(af1, bf, acc1, 0, 0, 0);
                acc2 = __builtin_amdgcn_mfma_f32_32x32x16_bf16(af2, bf, acc2, 0, 0, 0);
                acc3 = __builtin_amdgcn_mfma_f32_32x32x16_bf16(af3, bf, acc3, 0, 0, 0);
            }
        }
    }

    // epilogue: transposed partials numw[chunk][kcol][i] (coalesced over i)
    float* nb = numw + (size_t)chunk * FOUT * NN;
    const size_t col = (size_t)iw0 + l31;
    #pragma unroll
    for (int r = 0; r < 16; ++r) {
        const int mrow = (r & 3) + 8 * (r >> 2) + 4 * l5;
        nb[(size_t)(mrow)      * NN + col] = acc0[r];
        nb[(size_t)(mrow + 32) * NN + col] = acc1[r];
        nb[(size_t)(mrow + 64) * NN + col] = acc2[r];
        nb[(size_t)(mrow + 96) * NN + col] = acc3[r];
    }
    dacc += __shfl_xor(dacc, 32);
    if (l5 == 0) dpart[(size_t)chunk * NN + iw0 + l31] = dacc;
}

// ---------------------------------------------------------------------------
// Pass C: out[i][f] = elu( sum_c numw[c][f][i] / sum_c dpart[c][i] )
// ---------------------------------------------------------------------------
__global__ __launch_bounds__(256)
void gat_reduce(const float* __restrict__ numw, const float* __restrict__ dpart,
                float* __restrict__ out, int nchunk) {
    const int idx4 = blockIdx.x * 256 + threadIdx.x;   // over FOUT * NN/4
    const int f = idx4 >> 11;                          // NN/4 = 2048
    const int i4 = idx4 & 2047;
    float4 s = {0.f, 0.f, 0.f, 0.f};
    float4 d = {0.f, 0.f, 0.f, 0.f};
    for (int c = 0; c < nchunk; ++c) {
        const float4 v = *(const float4*)(numw + ((size_t)c * FOUT + f) * NN + (size_t)i4 * 4);
        s.x += v.x; s.y += v.y; s.z += v.z; s.w += v.w;
        const float4 dv = *(const float4*)(dpart + (size_t)c * NN + (size_t)i4 * 4);
        d.x += dv.x; d.y += dv.y; d.z += dv.z; d.w += dv.w;
    }
    float v;
    v = s.x / d.x; out[(size_t)(i4 * 4 + 0) * FOUT + f] = (v > 0.f) ? v : expm1f(v);
    v = s.y / d.y; out[(size_t)(i4 * 4 + 1) * FOUT + f] = (v > 0.f) ? v : expm1f(v);
    v = s.z / d.z; out[(size_t)(i4 * 4 + 2) * FOUT + f] = (v > 0.f) ? v : expm1f(v);
    v = s.w / d.w; out[(size_t)(i4 * 4 + 3) * FOUT + f] = (v > 0.f) ? v : expm1f(v);
}

// ---------------------------------------------------------------------------
extern "C" void kernel_launch(void* const* d_in, const int* in_sizes, int n_in,
                              void* d_out, int out_size, void* d_ws, size_t ws_size,
                              hipStream_t stream) {
    const float* input = (const float*)d_in[0];
    const int*   adj   = (const int*)d_in[1];
    const float* Ww    = (const float*)d_in[2];
    const float* Wb    = (const float*)d_in[3];
    const float* aw    = (const float*)d_in[4];
    const float* ab    = (const float*)d_in[5];
    float* out = (float*)d_out;

    char* ws = (char*)d_ws;
    unsigned short* hT2 = (unsigned short*)ws;                // 2 MB
    float* s_buf = (float*)(ws + (size_t)FOUT * NN * 2);      // 32 KB
    float* t_buf = s_buf + NN;                                // 32 KB
    float* dpart = t_buf + NN;

    int nchunk = 8;
    while (nchunk > 1) {
        size_t need = (size_t)FOUT * NN * 2 + 2 * (size_t)NN * 4
                    + (size_t)nchunk * NN * 4
                    + (size_t)nchunk * NN * FOUT * 4;
        if (need <= ws_size) break;
        nchunk >>= 1;
    }
    float* numw = dpart + (size_t)nchunk * NN;
    const int jc = NN / nchunk;

    gat_pass_a<<<dim3(NN / 64), 256, 0, stream>>>(input, Ww, Wb, aw, ab, hT2, s_buf, t_buf);
    gat_pass_b<<<dim3(NN / IBLK, nchunk), 256, 0, stream>>>(adj, hT2, s_buf, t_buf, numw, dpart, jc);
    gat_reduce<<<dim3(FOUT * NN / 4 / 256), 256, 0, stream>>>(numw, dpart, out, nchunk);
}

// Round 4
// 124.873 us; speedup vs baseline: 1.9296x; 1.9296x over previous
//
#include <hip/hip_runtime.h>
#include <hip/hip_bf16.h>
#include <cmath>

#define NN 8192
#define FIN 256
#define FOUT 128
#define ROWS 32          // i-rows per pass_b block
#define WVS 8            // waves per pass_b block
#define WIN 512          // j per window
#define NWIN (NN / WIN)  // 16

// dynamic-LDS offsets (bytes)
#define RED_OFF  0                    // [8][128][32] f32 = 131072
#define DEN_OFF  131072               // [8][32] f32      = 1024
#define DENT_OFF 132096               // [32] f32         = 128
#define MASK_OFF 132224               // 2 x [8 words][32 rows] u64 = 4096
#define SMEM_SZ  136320

typedef short short8 __attribute__((ext_vector_type(8)));
typedef float f32x16 __attribute__((ext_vector_type(16)));

static __device__ __forceinline__ unsigned short f2bf(float f) {
    unsigned u = __float_as_uint(f);
    u += 0x7fffu + ((u >> 16) & 1u);
    return (unsigned short)(u >> 16);
}

// ---------------------------------------------------------------------------
// Pass A: h = input @ W^T + Wb (bf16 MFMA). Writes hT2 j-tiled [j>>6][FOUT][j&63],
// s[i] = h·a1, t[j] = h·a2 + ab.
// ---------------------------------------------------------------------------
__global__ __launch_bounds__(256, 2)
void gat_pass_a(const float* __restrict__ input, const float* __restrict__ W,
                const float* __restrict__ Wb, const float* __restrict__ aw,
                const float* __restrict__ ab, unsigned short* __restrict__ hT2,
                float* __restrict__ s_out, float* __restrict__ t_out) {
    const int tid = threadIdx.x;
    const int w = tid >> 6, l = tid & 63;
    const int l5 = l >> 5, l31 = l & 31;
    const int nt = w >> 1, mh = w & 1;
    const int bx = blockIdx.x;
    const int i = bx * 64 + nt * 32 + l31;

    f32x16 acc0 = {}; f32x16 acc1 = {};
    #pragma unroll
    for (int ks = 0; ks < FIN / 16; ++ks) {
        const int c0 = ks * 16 + l5 * 8;
        const float4 b0 = *(const float4*)(input + (size_t)i * FIN + c0);
        const float4 b1 = *(const float4*)(input + (size_t)i * FIN + c0 + 4);
        short8 bf;
        bf[0]=(short)f2bf(b0.x); bf[1]=(short)f2bf(b0.y); bf[2]=(short)f2bf(b0.z); bf[3]=(short)f2bf(b0.w);
        bf[4]=(short)f2bf(b1.x); bf[5]=(short)f2bf(b1.y); bf[6]=(short)f2bf(b1.z); bf[7]=(short)f2bf(b1.w);
        {
            const int kcol = l31 + 32 * (2 * mh + 0);
            const float4 a0 = *(const float4*)(W + (size_t)kcol * FIN + c0);
            const float4 a1 = *(const float4*)(W + (size_t)kcol * FIN + c0 + 4);
            short8 af;
            af[0]=(short)f2bf(a0.x); af[1]=(short)f2bf(a0.y); af[2]=(short)f2bf(a0.z); af[3]=(short)f2bf(a0.w);
            af[4]=(short)f2bf(a1.x); af[5]=(short)f2bf(a1.y); af[6]=(short)f2bf(a1.z); af[7]=(short)f2bf(a1.w);
            acc0 = __builtin_amdgcn_mfma_f32_32x32x16_bf16(af, bf, acc0, 0, 0, 0);
        }
        {
            const int kcol = l31 + 32 * (2 * mh + 1);
            const float4 a0 = *(const float4*)(W + (size_t)kcol * FIN + c0);
            const float4 a1 = *(const float4*)(W + (size_t)kcol * FIN + c0 + 4);
            short8 af;
            af[0]=(short)f2bf(a0.x); af[1]=(short)f2bf(a0.y); af[2]=(short)f2bf(a0.z); af[3]=(short)f2bf(a0.w);
            af[4]=(short)f2bf(a1.x); af[5]=(short)f2bf(a1.y); af[6]=(short)f2bf(a1.z); af[7]=(short)f2bf(a1.w);
            acc1 = __builtin_amdgcn_mfma_f32_32x32x16_bf16(af, bf, acc1, 0, 0, 0);
        }
    }
    __shared__ float sred[4][32];
    __shared__ float tred[4][32];
    float sacc = 0.f, tacc = 0.f;
    #pragma unroll
    for (int m = 0; m < 2; ++m) {
        #pragma unroll
        for (int r = 0; r < 16; ++r) {
            const int kcol = 32 * (2 * mh + m) + 4 * l5 + (r & 3) + 8 * (r >> 2);
            const float hv = (m ? acc1[r] : acc0[r]) + Wb[kcol];
            hT2[((size_t)bx * FOUT + kcol) * 64 + (nt * 32 + l31)] = f2bf(hv);
            sacc += hv * aw[kcol];
            tacc += hv * aw[FOUT + kcol];
        }
    }
    sacc += __shfl_xor(sacc, 32);
    tacc += __shfl_xor(tacc, 32);
    if (l < 32) { sred[w][l] = sacc; tred[w][l] = tacc; }
    __syncthreads();
    if (mh == 0 && l < 32) {
        s_out[i] = sred[w][l] + sred[w + 1][l];
        t_out[i] = tred[w][l] + tred[w + 1][l] + ab[0];
    }
}

// ---------------------------------------------------------------------------
// Pass B (fused, complete): block = 8 waves, 32 i-rows, ALL j. Per 512-j
// window: contiguous adj loads + ballot -> LDS masks (double-buffered,
// prefetched one window ahead); each wave computes its 64-j slice with
// 32x32x16 MFMA (hT2 frags from L2). Cross-wave LDS reduce, div+elu, store.
// ---------------------------------------------------------------------------
__global__ __launch_bounds__(512, 1)
void gat_pass_b(const int* __restrict__ adj, const unsigned short* __restrict__ hT2,
                const float* __restrict__ s_in, const float* __restrict__ t_in,
                float* __restrict__ out) {
    extern __shared__ char smem[];
    const int tid = threadIdx.x;
    const int wv = tid >> 6, l = tid & 63;
    const int l5 = l >> 5, l31 = l & 31;
    const int i0 = blockIdx.x * ROWS;
    const float si = s_in[i0 + l31];

    f32x16 acc0 = {}, acc1 = {}, acc2 = {}, acc3 = {};
    float dacc = 0.f;

    const int* arow = adj + (size_t)(i0 + wv * 4) * NN;   // this wave's 4 adj rows
    unsigned long long* mask0 = (unsigned long long*)(smem + MASK_OFF);
    unsigned long long* mask1 = (unsigned long long*)(smem + MASK_OFF + 2048);

    int4 R[8];
    // ---- prologue: window 0 masks ----
    #pragma unroll
    for (int rr = 0; rr < 4; ++rr)
        #pragma unroll
        for (int g = 0; g < 2; ++g)
            R[rr * 2 + g] = *(const int4*)(arow + (size_t)rr * NN + g * 256 + l * 4);
    #pragma unroll
    for (int rr = 0; rr < 4; ++rr) {
        const int r = wv * 4 + rr;
        #pragma unroll
        for (int g = 0; g < 2; ++g) {
            const int4 a = R[rr * 2 + g];
            const unsigned long long b0 = __ballot(a.x > 0);
            const unsigned long long b1 = __ballot(a.y > 0);
            const unsigned long long b2 = __ballot(a.z > 0);
            const unsigned long long b3 = __ballot(a.w > 0);
            const unsigned long long v = (l & 2) ? ((l & 1) ? b3 : b2)
                                                 : ((l & 1) ? b1 : b0);
            if (l < 4) mask0[(g * 4 + l) * 32 + r] = v;
        }
    }
    __syncthreads();

    const int gsel = wv >> 2;             // which 256-j group of the window
    const int bitbase = (wv & 3) * 16;

    for (int w = 0; w < NWIN; ++w) {
        const int jwin = w * WIN;
        // ---- issue next-window adj loads (latency hides under compute) ----
        if (w + 1 < NWIN) {
            #pragma unroll
            for (int rr = 0; rr < 4; ++rr)
                #pragma unroll
                for (int gg = 0; gg < 2; ++gg)
                    R[rr * 2 + gg] = *(const int4*)(arow + (size_t)rr * NN +
                                                    (jwin + WIN) + gg * 256 + l * 4);
        }
        // ---- compute window w from LDS masks ----
        const unsigned long long* mb = (w & 1) ? mask1 : mask0;
        const unsigned long long m0 = mb[(gsel * 4 + 0) * 32 + l31];
        const unsigned long long m1 = mb[(gsel * 4 + 1) * 32 + l31];
        const unsigned long long m2 = mb[(gsel * 4 + 2) * 32 + l31];
        const unsigned long long m3 = mb[(gsel * 4 + 3) * 32 + l31];
        const int j0 = jwin + wv * 64;
        const int jt = j0 >> 6;
        #pragma unroll
        for (int kg = 0; kg < 4; ++kg) {
            const int bb = bitbase + kg * 4 + l5 * 2;
            const float4 t0 = *(const float4*)(t_in + j0 + kg * 16 + l5 * 8);
            const float4 t1 = *(const float4*)(t_in + j0 + kg * 16 + l5 * 8 + 4);
            short8 bf;
            float x, p;
            x = si + t0.x; x = fmaxf(x, 0.2f * x); p = __expf(x);
            p = ((m0 >> bb) & 1ull) ? p : 0.f; dacc += p; bf[0] = (short)f2bf(p);
            x = si + t0.y; x = fmaxf(x, 0.2f * x); p = __expf(x);
            p = ((m1 >> bb) & 1ull) ? p : 0.f; dacc += p; bf[1] = (short)f2bf(p);
            x = si + t0.z; x = fmaxf(x, 0.2f * x); p = __expf(x);
            p = ((m2 >> bb) & 1ull) ? p : 0.f; dacc += p; bf[2] = (short)f2bf(p);
            x = si + t0.w; x = fmaxf(x, 0.2f * x); p = __expf(x);
            p = ((m3 >> bb) & 1ull) ? p : 0.f; dacc += p; bf[3] = (short)f2bf(p);
            x = si + t1.x; x = fmaxf(x, 0.2f * x); p = __expf(x);
            p = ((m0 >> (bb + 1)) & 1ull) ? p : 0.f; dacc += p; bf[4] = (short)f2bf(p);
            x = si + t1.y; x = fmaxf(x, 0.2f * x); p = __expf(x);
            p = ((m1 >> (bb + 1)) & 1ull) ? p : 0.f; dacc += p; bf[5] = (short)f2bf(p);
            x = si + t1.z; x = fmaxf(x, 0.2f * x); p = __expf(x);
            p = ((m2 >> (bb + 1)) & 1ull) ? p : 0.f; dacc += p; bf[6] = (short)f2bf(p);
            x = si + t1.w; x = fmaxf(x, 0.2f * x); p = __expf(x);
            p = ((m3 >> (bb + 1)) & 1ull) ? p : 0.f; dacc += p; bf[7] = (short)f2bf(p);

            const unsigned short* fb = hT2 + ((size_t)jt * FOUT) * 64 + kg * 16 + l5 * 8;
            const short8 af0 = *(const short8*)(fb + (size_t)(l31)      * 64);
            const short8 af1 = *(const short8*)(fb + (size_t)(l31 + 32) * 64);
            const short8 af2 = *(const short8*)(fb + (size_t)(l31 + 64) * 64);
            const short8 af3 = *(const short8*)(fb + (size_t)(l31 + 96) * 64);
            acc0 = __builtin_amdgcn_mfma_f32_32x32x16_bf16(af0, bf, acc0, 0, 0, 0);
            acc1 = __builtin_amdgcn_mfma_f32_32x32x16_bf16(af1, bf, acc1, 0, 0, 0);
            acc2 = __builtin_amdgcn_mfma_f32_32x32x16_bf16(af2, bf, acc2, 0, 0, 0);
            acc3 = __builtin_amdgcn_mfma_f32_32x32x16_bf16(af3, bf, acc3, 0, 0, 0);
        }
        // ---- ballot next window into the other buffer ----
        if (w + 1 < NWIN) {
            unsigned long long* mw = ((w + 1) & 1) ? mask1 : mask0;
            #pragma unroll
            for (int rr = 0; rr < 4; ++rr) {
                const int r = wv * 4 + rr;
                #pragma unroll
                for (int gg = 0; gg < 2; ++gg) {
                    const int4 a = R[rr * 2 + gg];
                    const unsigned long long b0 = __ballot(a.x > 0);
                    const unsigned long long b1 = __ballot(a.y > 0);
                    const unsigned long long b2 = __ballot(a.z > 0);
                    const unsigned long long b3 = __ballot(a.w > 0);
                    const unsigned long long v = (l & 2) ? ((l & 1) ? b3 : b2)
                                                         : ((l & 1) ? b1 : b0);
                    if (l < 4) mw[(gg * 4 + l) * 32 + r] = v;
                }
            }
        }
        __syncthreads();
    }

    // ---- cross-wave reduction ----
    float* red = (float*)(smem + RED_OFF);
    {
        const int base = wv * 4096;
        #pragma unroll
        for (int r = 0; r < 16; ++r) {
            const int fr = (r & 3) + 8 * (r >> 2) + 4 * l5;
            red[base + (fr     ) * 32 + l31] = acc0[r];
            red[base + (fr + 32) * 32 + l31] = acc1[r];
            red[base + (fr + 64) * 32 + l31] = acc2[r];
            red[base + (fr + 96) * 32 + l31] = acc3[r];
        }
    }
    dacc += __shfl_xor(dacc, 32);
    float* den = (float*)(smem + DEN_OFF);
    if (l5 == 0) den[wv * 32 + l31] = dacc;
    __syncthreads();
    float* dent = (float*)(smem + DENT_OFF);
    if (tid < 32) {
        float d = 0.f;
        #pragma unroll
        for (int q = 0; q < WVS; ++q) d += den[q * 32 + tid];
        dent[tid] = d;
    }
    __syncthreads();
    // each thread: one f, 8 consecutive i
    const int f = tid >> 2;
    const int iq = (tid & 3) * 8;
    float s[8] = {0.f, 0.f, 0.f, 0.f, 0.f, 0.f, 0.f, 0.f};
    #pragma unroll
    for (int q = 0; q < WVS; ++q) {
        const float4 vA = *(const float4*)&red[q * 4096 + f * 32 + iq];
        const float4 vB = *(const float4*)&red[q * 4096 + f * 32 + iq + 4];
        s[0] += vA.x; s[1] += vA.y; s[2] += vA.z; s[3] += vA.w;
        s[4] += vB.x; s[5] += vB.y; s[6] += vB.z; s[7] += vB.w;
    }
    #pragma unroll
    for (int k = 0; k < 8; ++k) {
        const float v = s[k] / dent[iq + k];
        out[(size_t)(i0 + iq + k) * FOUT + f] = (v > 0.f) ? v : expm1f(v);
    }
}

// ---------------------------------------------------------------------------
extern "C" void kernel_launch(void* const* d_in, const int* in_sizes, int n_in,
                              void* d_out, int out_size, void* d_ws, size_t ws_size,
                              hipStream_t stream) {
    const float* input = (const float*)d_in[0];
    const int*   adj   = (const int*)d_in[1];
    const float* Ww    = (const float*)d_in[2];
    const float* Wb    = (const float*)d_in[3];
    const float* aw    = (const float*)d_in[4];
    const float* ab    = (const float*)d_in[5];
    float* out = (float*)d_out;

    char* ws = (char*)d_ws;
    unsigned short* hT2 = (unsigned short*)ws;               // 2 MB
    float* s_buf = (float*)(ws + (size_t)FOUT * NN * 2);     // 32 KB
    float* t_buf = s_buf + NN;                               // 32 KB

    gat_pass_a<<<dim3(NN / 64), 256, 0, stream>>>(input, Ww, Wb, aw, ab, hT2, s_buf, t_buf);
    gat_pass_b<<<dim3(NN / ROWS), 512, SMEM_SZ, stream>>>(adj, hT2, s_buf, t_buf, out);
}

// Round 5
// 120.407 us; speedup vs baseline: 2.0012x; 1.0371x over previous
//
#include <hip/hip_runtime.h>
#include <hip/hip_bf16.h>
#include <cmath>

#define NN 8192
#define FIN 256
#define FOUT 128
#define ROWS 32
#define JWIN 64

typedef short short8 __attribute__((ext_vector_type(8)));
typedef float f32x16 __attribute__((ext_vector_type(16)));

static __device__ __forceinline__ unsigned short f2bf(float f) {
    unsigned u = __float_as_uint(f);
    u += 0x7fffu + ((u >> 16) & 1u);
    return (unsigned short)(u >> 16);
}

// ---------------------------------------------------------------------------
// Pass A: h = input @ W^T + Wb (bf16 MFMA). Writes hT2 j-tiled [j>>6][FOUT][j&63],
// s[i] = h·a1, t[j] = h·a2 + ab.
// ---------------------------------------------------------------------------
__global__ __launch_bounds__(256, 2)
void gat_pass_a(const float* __restrict__ input, const float* __restrict__ W,
                const float* __restrict__ Wb, const float* __restrict__ aw,
                const float* __restrict__ ab, unsigned short* __restrict__ hT2,
                float* __restrict__ s_out, float* __restrict__ t_out) {
    const int tid = threadIdx.x;
    const int w = tid >> 6, l = tid & 63;
    const int l5 = l >> 5, l31 = l & 31;
    const int nt = w >> 1, mh = w & 1;
    const int bx = blockIdx.x;
    const int i = bx * 64 + nt * 32 + l31;

    f32x16 acc0 = {}; f32x16 acc1 = {};
    #pragma unroll
    for (int ks = 0; ks < FIN / 16; ++ks) {
        const int c0 = ks * 16 + l5 * 8;
        const float4 b0 = *(const float4*)(input + (size_t)i * FIN + c0);
        const float4 b1 = *(const float4*)(input + (size_t)i * FIN + c0 + 4);
        short8 bf;
        bf[0]=(short)f2bf(b0.x); bf[1]=(short)f2bf(b0.y); bf[2]=(short)f2bf(b0.z); bf[3]=(short)f2bf(b0.w);
        bf[4]=(short)f2bf(b1.x); bf[5]=(short)f2bf(b1.y); bf[6]=(short)f2bf(b1.z); bf[7]=(short)f2bf(b1.w);
        {
            const int kcol = l31 + 32 * (2 * mh + 0);
            const float4 a0 = *(const float4*)(W + (size_t)kcol * FIN + c0);
            const float4 a1 = *(const float4*)(W + (size_t)kcol * FIN + c0 + 4);
            short8 af;
            af[0]=(short)f2bf(a0.x); af[1]=(short)f2bf(a0.y); af[2]=(short)f2bf(a0.z); af[3]=(short)f2bf(a0.w);
            af[4]=(short)f2bf(a1.x); af[5]=(short)f2bf(a1.y); af[6]=(short)f2bf(a1.z); af[7]=(short)f2bf(a1.w);
            acc0 = __builtin_amdgcn_mfma_f32_32x32x16_bf16(af, bf, acc0, 0, 0, 0);
        }
        {
            const int kcol = l31 + 32 * (2 * mh + 1);
            const float4 a0 = *(const float4*)(W + (size_t)kcol * FIN + c0);
            const float4 a1 = *(const float4*)(W + (size_t)kcol * FIN + c0 + 4);
            short8 af;
            af[0]=(short)f2bf(a0.x); af[1]=(short)f2bf(a0.y); af[2]=(short)f2bf(a0.z); af[3]=(short)f2bf(a0.w);
            af[4]=(short)f2bf(a1.x); af[5]=(short)f2bf(a1.y); af[6]=(short)f2bf(a1.z); af[7]=(short)f2bf(a1.w);
            acc1 = __builtin_amdgcn_mfma_f32_32x32x16_bf16(af, bf, acc1, 0, 0, 0);
        }
    }
    __shared__ float sred[4][32];
    __shared__ float tred[4][32];
    float sacc = 0.f, tacc = 0.f;
    #pragma unroll
    for (int m = 0; m < 2; ++m) {
        #pragma unroll
        for (int r = 0; r < 16; ++r) {
            const int kcol = 32 * (2 * mh + m) + 4 * l5 + (r & 3) + 8 * (r >> 2);
            const float hv = (m ? acc1[r] : acc0[r]) + Wb[kcol];
            hT2[((size_t)bx * FOUT + kcol) * 64 + (nt * 32 + l31)] = f2bf(hv);
            sacc += hv * aw[kcol];
            tacc += hv * aw[FOUT + kcol];
        }
    }
    sacc += __shfl_xor(sacc, 32);
    tacc += __shfl_xor(tacc, 32);
    if (l < 32) { sred[w][l] = sacc; tred[w][l] = tacc; }
    __syncthreads();
    if (mh == 0 && l < 32) {
        s_out[i] = sred[w][l] + sred[w + 1][l];
        t_out[i] = tred[w][l] + tred[w + 1][l] + ab[0];
    }
}

// ---------------------------------------------------------------------------
// Pass B: 4-wave blocks, 32 i-rows x jc j-columns. Waves split the MFMA K dim
// (wave wv = 16-j slice of each 64-j window) so each exp is computed once.
// adj streamed contiguously (int4 + ballot -> u64/row masks in LDS, 1-window
// prefetch). K-split accs reduced in LDS, written as coalesced f32 partials.
// ---------------------------------------------------------------------------
__global__ __launch_bounds__(256, 4)
void gat_pass_b(const int* __restrict__ adj, const unsigned short* __restrict__ hT2,
                const float* __restrict__ s_in, const float* __restrict__ t_in,
                float* __restrict__ numw, float* __restrict__ dpart, int jc) {
    __shared__ float red[FOUT * ROWS];            // 16 KB
    __shared__ float denb[4][ROWS];               // 512 B
    __shared__ unsigned long long mbuf[2][ROWS];  // 512 B
    const int tid = threadIdx.x;
    const int wv = tid >> 6, l = tid & 63;
    const int l5 = l >> 5, l31 = l & 31;
    const int i0 = blockIdx.x * ROWS;
    const int chunk = blockIdx.y;
    const int jb = chunk * jc;
    const int nwin = jc / JWIN;
    const float si = s_in[i0 + l31];

    // adj mapping: load q covers rows i0 + wv*8 + q*4 + (l>>4), cols (l&15)*4 ..+3
    const int* abase = adj + (size_t)(i0 + wv * 8 + (l >> 4)) * NN + (l & 15) * 4;

    f32x16 acc0 = {}, acc1 = {}, acc2 = {}, acc3 = {};
    float dacc = 0.f;

    // pack: ballot 4 components, interleave 16-bit fields into u64 phase-words
    // mask bit layout for row: bit = 16*(joff&3) + (joff>>2), joff in [0,64)
    auto packq = [&](const int4& a, int q, unsigned long long* mb) {
        const unsigned long long b0 = __ballot(a.x > 0);
        const unsigned long long b1 = __ballot(a.y > 0);
        const unsigned long long b2 = __ballot(a.z > 0);
        const unsigned long long b3 = __ballot(a.w > 0);
        const int k = l & 3;
        const int sh = 16 * k;
        if ((l >> 2) == q) {
            const unsigned long long v = ((b0 >> sh) & 0xFFFFull)
                                       | (((b1 >> sh) & 0xFFFFull) << 16)
                                       | (((b2 >> sh) & 0xFFFFull) << 32)
                                       | (((b3 >> sh) & 0xFFFFull) << 48);
            mb[wv * 8 + q * 4 + k] = v;
        }
    };

    int4 R0 = *(const int4*)(abase + jb);
    int4 R1 = *(const int4*)(abase + 4 * NN + jb);
    packq(R0, 0, mbuf[0]);
    packq(R1, 1, mbuf[0]);

    const int bitb = wv * 4 + l5 * 2;

    for (int w = 0; w < nwin; ++w) {
        const int jw = jb + w * JWIN;
        __syncthreads();                         // masks for window w ready
        const unsigned long long m = mbuf[w & 1][l31] >> bitb;
        const int j0 = jw + wv * 16;             // this wave's 16-j K slice
        const float4 t0 = *(const float4*)(t_in + j0 + l5 * 8);
        const float4 t1 = *(const float4*)(t_in + j0 + l5 * 8 + 4);
        const unsigned short* fbp = hT2 + ((size_t)(jw >> 6) * FOUT + l31) * 64 + wv * 16 + l5 * 8;
        const short8 af0 = *(const short8*)(fbp);
        const short8 af1 = *(const short8*)(fbp + 2048);
        const short8 af2 = *(const short8*)(fbp + 4096);
        const short8 af3 = *(const short8*)(fbp + 6144);
        // prefetch next window's adj (issued after frag loads: vmcnt keeps them live)
        if (w + 1 < nwin) {
            R0 = *(const int4*)(abase + jw + JWIN);
            R1 = *(const int4*)(abase + 4 * NN + jw + JWIN);
        }
        // P build: joff = wv*16 + l5*8 + e; bit(e) = bitb + 16*(e&3) + (e>>2)
        short8 bf;
        float x, p;
        x = si + t0.x; x = fmaxf(x, 0.2f * x); p = __expf(x);
        p = ((m >> 0)  & 1ull) ? p : 0.f; dacc += p; bf[0] = (short)f2bf(p);
        x = si + t0.y; x = fmaxf(x, 0.2f * x); p = __expf(x);
        p = ((m >> 16) & 1ull) ? p : 0.f; dacc += p; bf[1] = (short)f2bf(p);
        x = si + t0.z; x = fmaxf(x, 0.2f * x); p = __expf(x);
        p = ((m >> 32) & 1ull) ? p : 0.f; dacc += p; bf[2] = (short)f2bf(p);
        x = si + t0.w; x = fmaxf(x, 0.2f * x); p = __expf(x);
        p = ((m >> 48) & 1ull) ? p : 0.f; dacc += p; bf[3] = (short)f2bf(p);
        x = si + t1.x; x = fmaxf(x, 0.2f * x); p = __expf(x);
        p = ((m >> 1)  & 1ull) ? p : 0.f; dacc += p; bf[4] = (short)f2bf(p);
        x = si + t1.y; x = fmaxf(x, 0.2f * x); p = __expf(x);
        p = ((m >> 17) & 1ull) ? p : 0.f; dacc += p; bf[5] = (short)f2bf(p);
        x = si + t1.z; x = fmaxf(x, 0.2f * x); p = __expf(x);
        p = ((m >> 33) & 1ull) ? p : 0.f; dacc += p; bf[6] = (short)f2bf(p);
        x = si + t1.w; x = fmaxf(x, 0.2f * x); p = __expf(x);
        p = ((m >> 49) & 1ull) ? p : 0.f; dacc += p; bf[7] = (short)f2bf(p);

        acc0 = __builtin_amdgcn_mfma_f32_32x32x16_bf16(af0, bf, acc0, 0, 0, 0);
        acc1 = __builtin_amdgcn_mfma_f32_32x32x16_bf16(af1, bf, acc1, 0, 0, 0);
        acc2 = __builtin_amdgcn_mfma_f32_32x32x16_bf16(af2, bf, acc2, 0, 0, 0);
        acc3 = __builtin_amdgcn_mfma_f32_32x32x16_bf16(af3, bf, acc3, 0, 0, 0);

        if (w + 1 < nwin) {
            unsigned long long* mb = mbuf[(w + 1) & 1];
            packq(R0, 0, mb);
            packq(R1, 1, mb);
        }
    }

    // ---- cross-wave K reduction (phased, compile-time ph) ----
    #pragma unroll
    for (int ph = 0; ph < 4; ++ph) {
        __syncthreads();
        if (wv == ph) {
            #pragma unroll
            for (int r = 0; r < 16; ++r) {
                const int fr = (r & 3) + 8 * (r >> 2) + 4 * l5;
                if (ph == 0) {
                    red[(fr     ) * ROWS + l31] = acc0[r];
                    red[(fr + 32) * ROWS + l31] = acc1[r];
                    red[(fr + 64) * ROWS + l31] = acc2[r];
                    red[(fr + 96) * ROWS + l31] = acc3[r];
                } else {
                    red[(fr     ) * ROWS + l31] += acc0[r];
                    red[(fr + 32) * ROWS + l31] += acc1[r];
                    red[(fr + 64) * ROWS + l31] += acc2[r];
                    red[(fr + 96) * ROWS + l31] += acc3[r];
                }
            }
        }
    }
    dacc += __shfl_xor(dacc, 32);
    if (l5 == 0) denb[wv][l31] = dacc;
    __syncthreads();

    // coalesced partial writes: numw[chunk][f][i]
    #pragma unroll
    for (int e = 0; e < 4; ++e) {
        const int f = e * 32 + (tid >> 3);
        const int io = (tid & 7) * 4;
        *(float4*)(numw + ((size_t)chunk * FOUT + f) * NN + i0 + io) =
            *(const float4*)(red + f * ROWS + io);
    }
    if (tid < ROWS)
        dpart[(size_t)chunk * NN + i0 + tid] =
            denb[0][tid] + denb[1][tid] + denb[2][tid] + denb[3][tid];
}

// ---------------------------------------------------------------------------
// Pass C: out[i][f] = elu( sum_c numw[c][f][i] / sum_c dpart[c][i] )
// LDS transpose so loads AND stores are contiguous.
// ---------------------------------------------------------------------------
__global__ __launch_bounds__(256)
void gat_reduce(const float* __restrict__ numw, const float* __restrict__ dpart,
                float* __restrict__ out, int nchunk) {
    __shared__ float tile[FOUT * 33];
    __shared__ float dent[32];
    const int t = threadIdx.x;
    const int i0 = blockIdx.x * 32;
    if (t < 32) {
        float d = 0.f;
        for (int c = 0; c < nchunk; ++c) d += dpart[(size_t)c * NN + i0 + t];
        dent[t] = d;
    }
    __syncthreads();
    #pragma unroll
    for (int e = 0; e < 4; ++e) {
        const int f = e * 32 + (t >> 3);
        const int io = (t & 7) * 4;
        float4 s = {0.f, 0.f, 0.f, 0.f};
        for (int c = 0; c < nchunk; ++c) {
            const float4 v = *(const float4*)(numw + ((size_t)c * FOUT + f) * NN + i0 + io);
            s.x += v.x; s.y += v.y; s.z += v.z; s.w += v.w;
        }
        float v;
        v = s.x / dent[io + 0]; tile[f * 33 + io + 0] = (v > 0.f) ? v : expm1f(v);
        v = s.y / dent[io + 1]; tile[f * 33 + io + 1] = (v > 0.f) ? v : expm1f(v);
        v = s.z / dent[io + 2]; tile[f * 33 + io + 2] = (v > 0.f) ? v : expm1f(v);
        v = s.w / dent[io + 3]; tile[f * 33 + io + 3] = (v > 0.f) ? v : expm1f(v);
    }
    __syncthreads();
    #pragma unroll
    for (int e = 0; e < 4; ++e) {
        const int row = (t >> 5) * 4 + e;
        const int fo = (t & 31) * 4;
        const float4 v = { tile[(fo + 0) * 33 + row], tile[(fo + 1) * 33 + row],
                           tile[(fo + 2) * 33 + row], tile[(fo + 3) * 33 + row] };
        *(float4*)(out + (size_t)(i0 + row) * FOUT + fo) = v;
    }
}

// ---------------------------------------------------------------------------
extern "C" void kernel_launch(void* const* d_in, const int* in_sizes, int n_in,
                              void* d_out, int out_size, void* d_ws, size_t ws_size,
                              hipStream_t stream) {
    const float* input = (const float*)d_in[0];
    const int*   adj   = (const int*)d_in[1];
    const float* Ww    = (const float*)d_in[2];
    const float* Wb    = (const float*)d_in[3];
    const float* aw    = (const float*)d_in[4];
    const float* ab    = (const float*)d_in[5];
    float* out = (float*)d_out;

    char* ws = (char*)d_ws;
    unsigned short* hT2 = (unsigned short*)ws;               // 2 MB
    float* s_buf = (float*)(ws + (size_t)FOUT * NN * 2);     // 32 KB
    float* t_buf = s_buf + NN;                               // 32 KB

    int nchunk = 4;
    while (nchunk > 1) {
        size_t need = (size_t)FOUT * NN * 2 + 2 * (size_t)NN * 4
                    + (size_t)nchunk * NN * 4
                    + (size_t)nchunk * NN * FOUT * 4;
        if (need <= ws_size) break;
        nchunk >>= 1;
    }
    float* dpart = t_buf + NN;
    float* numw = dpart + (size_t)nchunk * NN;
    const int jc = NN / nchunk;

    gat_pass_a<<<dim3(NN / 64), 256, 0, stream>>>(input, Ww, Wb, aw, ab, hT2, s_buf, t_buf);
    gat_pass_b<<<dim3(NN / ROWS, nchunk), 256, 0, stream>>>(adj, hT2, s_buf, t_buf, numw, dpart, jc);
    gat_reduce<<<dim3(NN / 32), 256, 0, stream>>>(numw, dpart, out, nchunk);
}

// Round 6
// 115.512 us; speedup vs baseline: 2.0860x; 1.0424x over previous
//
#include <hip/hip_runtime.h>
#include <hip/hip_bf16.h>
#include <cmath>

#define NN 8192
#define FIN 256
#define FOUT 128
#define ROWS 32
#define NCH 4
#define JC (NN / NCH)        // 2048 per chunk
#define JSPAN (JC / 4)       // 512 per wave
#define NWIN (JSPAN / 64)    // 8 windows of 64 j per wave

typedef short short8 __attribute__((ext_vector_type(8)));
typedef float f32x16 __attribute__((ext_vector_type(16)));
typedef unsigned long long u64;

static __device__ __forceinline__ unsigned short f2bf(float f) {
    unsigned u = __float_as_uint(f);
    u += 0x7fffu + ((u >> 16) & 1u);
    return (unsigned short)(u >> 16);
}

// ---------------------------------------------------------------------------
// Pass A: h = input @ W^T + Wb (bf16 MFMA). Writes hT3 in EXACT MFMA A-frag
// order: hT3[tile][fg][ks][lane][e] = h[fg*32+(lane&31)][tile*64+ks*16+(lane>>5)*8+e]
// so pass_b frag loads are 64-lane-contiguous 1KB. Also s = h·a1, t = h·a2+ab.
// ---------------------------------------------------------------------------
__global__ __launch_bounds__(256, 2)
void gat_pass_a(const float* __restrict__ input, const float* __restrict__ W,
                const float* __restrict__ Wb, const float* __restrict__ aw,
                const float* __restrict__ ab, unsigned short* __restrict__ hT3,
                float* __restrict__ s_out, float* __restrict__ t_out) {
    const int tid = threadIdx.x;
    const int w = tid >> 6, l = tid & 63;
    const int l5 = l >> 5, l31 = l & 31;
    const int nt = w >> 1, mh = w & 1;
    const int bx = blockIdx.x;
    const int i = bx * 64 + nt * 32 + l31;

    f32x16 acc0 = {}; f32x16 acc1 = {};
    #pragma unroll
    for (int ks = 0; ks < FIN / 16; ++ks) {
        const int c0 = ks * 16 + l5 * 8;
        const float4 b0 = *(const float4*)(input + (size_t)i * FIN + c0);
        const float4 b1 = *(const float4*)(input + (size_t)i * FIN + c0 + 4);
        short8 bf;
        bf[0]=(short)f2bf(b0.x); bf[1]=(short)f2bf(b0.y); bf[2]=(short)f2bf(b0.z); bf[3]=(short)f2bf(b0.w);
        bf[4]=(short)f2bf(b1.x); bf[5]=(short)f2bf(b1.y); bf[6]=(short)f2bf(b1.z); bf[7]=(short)f2bf(b1.w);
        {
            const int kcol = l31 + 32 * (2 * mh + 0);
            const float4 a0 = *(const float4*)(W + (size_t)kcol * FIN + c0);
            const float4 a1 = *(const float4*)(W + (size_t)kcol * FIN + c0 + 4);
            short8 af;
            af[0]=(short)f2bf(a0.x); af[1]=(short)f2bf(a0.y); af[2]=(short)f2bf(a0.z); af[3]=(short)f2bf(a0.w);
            af[4]=(short)f2bf(a1.x); af[5]=(short)f2bf(a1.y); af[6]=(short)f2bf(a1.z); af[7]=(short)f2bf(a1.w);
            acc0 = __builtin_amdgcn_mfma_f32_32x32x16_bf16(af, bf, acc0, 0, 0, 0);
        }
        {
            const int kcol = l31 + 32 * (2 * mh + 1);
            const float4 a0 = *(const float4*)(W + (size_t)kcol * FIN + c0);
            const float4 a1 = *(const float4*)(W + (size_t)kcol * FIN + c0 + 4);
            short8 af;
            af[0]=(short)f2bf(a0.x); af[1]=(short)f2bf(a0.y); af[2]=(short)f2bf(a0.z); af[3]=(short)f2bf(a0.w);
            af[4]=(short)f2bf(a1.x); af[5]=(short)f2bf(a1.y); af[6]=(short)f2bf(a1.z); af[7]=(short)f2bf(a1.w);
            acc1 = __builtin_amdgcn_mfma_f32_32x32x16_bf16(af, bf, acc1, 0, 0, 0);
        }
    }
    __shared__ float sred[4][32];
    __shared__ float tred[4][32];
    float sacc = 0.f, tacc = 0.f;
    const int jloc = nt * 32 + l31;                 // j = bx*64 + jloc
    const int ksb = jloc >> 4;                      // k-slice within tile
    const int lane_j = 32 * ((jloc >> 3) & 1);      // (j>>3)&1 -> lane bit5
    const int e = jloc & 7;
    #pragma unroll
    for (int m = 0; m < 2; ++m) {
        #pragma unroll
        for (int r = 0; r < 16; ++r) {
            const int kcol = 32 * (2 * mh + m) + 4 * l5 + (r & 3) + 8 * (r >> 2);
            const float hv = (m ? acc1[r] : acc0[r]) + Wb[kcol];
            const int fg = kcol >> 5;
            const int lane = (kcol & 31) + lane_j;
            hT3[((((size_t)bx * 4 + fg) * 4 + ksb) * 64 + lane) * 8 + e] = f2bf(hv);
            sacc += hv * aw[kcol];
            tacc += hv * aw[FOUT + kcol];
        }
    }
    sacc += __shfl_xor(sacc, 32);
    tacc += __shfl_xor(tacc, 32);
    if (l < 32) { sred[w][l] = sacc; tred[w][l] = tacc; }
    __syncthreads();
    if (mh == 0 && l < 32) {
        s_out[i] = sred[w][l] + sred[w + 1][l];
        t_out[i] = tred[w][l] + tred[w + 1][l] + ab[0];
    }
}

// ---------------------------------------------------------------------------
// Pass B: 4 waves/block, same 32 i-rows, DISJOINT 512-j spans -> barrier-free
// main loop. adj streamed contiguously (8 int4/window, 1-window prefetch),
// ballot -> wave-private LDS mask words (no cross-wave sync). A-frags from
// hT3 are perfectly coalesced 1KB loads. Epilogue: cross-wave LDS reduce,
// coalesced f32 partial writes.
// ---------------------------------------------------------------------------
__global__ __launch_bounds__(256, 3)
void gat_pass_b(const int* __restrict__ adj, const unsigned short* __restrict__ hT3,
                const float* __restrict__ s_in, const float* __restrict__ t_in,
                float* __restrict__ numw, float* __restrict__ dpart) {
    __shared__ float red[FOUT * ROWS];       // 16 KB
    __shared__ float denb[4][ROWS];          // 512 B
    __shared__ u64 mbuf[4][2][ROWS];         // 2 KB, wave-private [wv]
    const int tid = threadIdx.x;
    const int wv = tid >> 6, l = tid & 63;
    const int l5 = l >> 5, l31 = l & 31;
    const int i0 = blockIdx.x * ROWS;
    const int chunk = blockIdx.y;
    const int jwv = chunk * JC + wv * JSPAN;
    const float si = s_in[i0 + l31];

    // adj: load q covers rows i0 + q*4 + (l>>4), cols jwv + w*64 + (l&15)*4..+3
    const int* ab = adj + (size_t)(i0 + (l >> 4)) * NN + (l & 15) * 4 + jwv;
    u64* mb = &mbuf[wv][0][0];

    f32x16 acc0 = {}, acc1 = {}, acc2 = {}, acc3 = {};
    float dacc = 0.f;

    int4 R[8];
    const int kk = l & 3;
    const int sh = 16 * kk;
    const int lq = l >> 2;

    // pack this window's 8 loads into 32 mask words (rows 0..31 local)
    // word(q*4+k) = row q*4+k's 64 bits: bit 16*c + m <-> col 4m + c
    #define PACKQ(q, buf)                                                        \
    {                                                                            \
        const int4 a = R[q];                                                     \
        const u64 b0 = __ballot(a.x > 0);                                        \
        const u64 b1 = __ballot(a.y > 0);                                        \
        const u64 b2 = __ballot(a.z > 0);                                        \
        const u64 b3 = __ballot(a.w > 0);                                        \
        const u64 v = ((b0 >> sh) & 0xFFFFull) | (((b1 >> sh) & 0xFFFFull) << 16)\
                    | (((b2 >> sh) & 0xFFFFull) << 32)                           \
                    | (((b3 >> sh) & 0xFFFFull) << 48);                          \
        if (lq == (q)) mb[(buf) * ROWS + (q) * 4 + kk] = v;                      \
    }

    // prologue: window 0
    #pragma unroll
    for (int q = 0; q < 8; ++q) R[q] = *(const int4*)(ab + (size_t)q * 4 * NN);
    #pragma unroll
    for (int q = 0; q < 8; ++q) PACKQ(q, 0)
    __builtin_amdgcn_wave_barrier();

    for (int w = 0; w < NWIN; ++w) {
        const u64 myw = mb[(w & 1) * ROWS + l31];
        // issue next window's adj loads early (consumed at end of this window)
        if (w + 1 < NWIN) {
            #pragma unroll
            for (int q = 0; q < 8; ++q)
                R[q] = *(const int4*)(ab + (size_t)q * 4 * NN + (w + 1) * 64);
        }
        const int tile = (jwv + w * 64) >> 6;
        #pragma unroll
        for (int ks = 0; ks < 4; ++ks) {
            const int jsl = jwv + w * 64 + ks * 16 + l5 * 8;
            const float4 t0 = *(const float4*)(t_in + jsl);
            const float4 t1 = *(const float4*)(t_in + jsl + 4);
            const u64 m = myw >> (ks * 4 + l5 * 2);
            short8 bf;
            float x, p;
            x = si + t0.x; x = fmaxf(x, 0.2f * x); p = __expf(x);
            p = ((m >> 0)  & 1ull) ? p : 0.f; dacc += p; bf[0] = (short)f2bf(p);
            x = si + t0.y; x = fmaxf(x, 0.2f * x); p = __expf(x);
            p = ((m >> 16) & 1ull) ? p : 0.f; dacc += p; bf[1] = (short)f2bf(p);
            x = si + t0.z; x = fmaxf(x, 0.2f * x); p = __expf(x);
            p = ((m >> 32) & 1ull) ? p : 0.f; dacc += p; bf[2] = (short)f2bf(p);
            x = si + t0.w; x = fmaxf(x, 0.2f * x); p = __expf(x);
            p = ((m >> 48) & 1ull) ? p : 0.f; dacc += p; bf[3] = (short)f2bf(p);
            x = si + t1.x; x = fmaxf(x, 0.2f * x); p = __expf(x);
            p = ((m >> 1)  & 1ull) ? p : 0.f; dacc += p; bf[4] = (short)f2bf(p);
            x = si + t1.y; x = fmaxf(x, 0.2f * x); p = __expf(x);
            p = ((m >> 17) & 1ull) ? p : 0.f; dacc += p; bf[5] = (short)f2bf(p);
            x = si + t1.z; x = fmaxf(x, 0.2f * x); p = __expf(x);
            p = ((m >> 33) & 1ull) ? p : 0.f; dacc += p; bf[6] = (short)f2bf(p);
            x = si + t1.w; x = fmaxf(x, 0.2f * x); p = __expf(x);
            p = ((m >> 49) & 1ull) ? p : 0.f; dacc += p; bf[7] = (short)f2bf(p);

            // A-frags: 64-lane contiguous 1KB loads from hT3
            const unsigned short* hp =
                hT3 + (((size_t)tile * 4) * 4 + ks) * 512 + (size_t)l * 8;
            const short8 af0 = *(const short8*)(hp);
            const short8 af1 = *(const short8*)(hp + 2048);
            const short8 af2 = *(const short8*)(hp + 4096);
            const short8 af3 = *(const short8*)(hp + 6144);
            acc0 = __builtin_amdgcn_mfma_f32_32x32x16_bf16(af0, bf, acc0, 0, 0, 0);
            acc1 = __builtin_amdgcn_mfma_f32_32x32x16_bf16(af1, bf, acc1, 0, 0, 0);
            acc2 = __builtin_amdgcn_mfma_f32_32x32x16_bf16(af2, bf, acc2, 0, 0, 0);
            acc3 = __builtin_amdgcn_mfma_f32_32x32x16_bf16(af3, bf, acc3, 0, 0, 0);
        }
        // ballot + store masks for next window (wave-private, no barrier)
        if (w + 1 < NWIN) {
            #pragma unroll
            for (int q = 0; q < 8; ++q) PACKQ(q, (w + 1) & 1)
        }
        __builtin_amdgcn_wave_barrier();
    }
    #undef PACKQ

    // ---- cross-wave reduction (j-split partials of same rows) ----
    #pragma unroll
    for (int ph = 0; ph < 4; ++ph) {
        __syncthreads();
        if (wv == ph) {
            #pragma unroll
            for (int r = 0; r < 16; ++r) {
                const int fr = (r & 3) + 8 * (r >> 2) + 4 * l5;
                if (ph == 0) {
                    red[(fr     ) * ROWS + l31] = acc0[r];
                    red[(fr + 32) * ROWS + l31] = acc1[r];
                    red[(fr + 64) * ROWS + l31] = acc2[r];
                    red[(fr + 96) * ROWS + l31] = acc3[r];
                } else {
                    red[(fr     ) * ROWS + l31] += acc0[r];
                    red[(fr + 32) * ROWS + l31] += acc1[r];
                    red[(fr + 64) * ROWS + l31] += acc2[r];
                    red[(fr + 96) * ROWS + l31] += acc3[r];
                }
            }
        }
    }
    dacc += __shfl_xor(dacc, 32);
    if (l5 == 0) denb[wv][l31] = dacc;
    __syncthreads();

    float* nb = numw + (size_t)chunk * FOUT * NN;
    #pragma unroll
    for (int e = 0; e < 4; ++e) {
        const int f = e * 32 + (tid >> 3);
        const int io = (tid & 7) * 4;
        *(float4*)(nb + (size_t)f * NN + i0 + io) = *(const float4*)(red + f * ROWS + io);
    }
    if (tid < ROWS)
        dpart[(size_t)chunk * NN + i0 + tid] =
            denb[0][tid] + denb[1][tid] + denb[2][tid] + denb[3][tid];
}

// ---------------------------------------------------------------------------
// Pass C: out[i][f] = elu( sum_c numw[c][f][i] / sum_c dpart[c][i] )
// ---------------------------------------------------------------------------
__global__ __launch_bounds__(256)
void gat_reduce(const float* __restrict__ numw, const float* __restrict__ dpart,
                float* __restrict__ out, int nchunk) {
    __shared__ float tile[FOUT * 33];
    __shared__ float dent[32];
    const int t = threadIdx.x;
    const int i0 = blockIdx.x * 32;
    if (t < 32) {
        float d = 0.f;
        for (int c = 0; c < nchunk; ++c) d += dpart[(size_t)c * NN + i0 + t];
        dent[t] = d;
    }
    __syncthreads();
    #pragma unroll
    for (int e = 0; e < 4; ++e) {
        const int f = e * 32 + (t >> 3);
        const int io = (t & 7) * 4;
        float4 s = {0.f, 0.f, 0.f, 0.f};
        for (int c = 0; c < nchunk; ++c) {
            const float4 v = *(const float4*)(numw + ((size_t)c * FOUT + f) * NN + i0 + io);
            s.x += v.x; s.y += v.y; s.z += v.z; s.w += v.w;
        }
        float v;
        v = s.x / dent[io + 0]; tile[f * 33 + io + 0] = (v > 0.f) ? v : expm1f(v);
        v = s.y / dent[io + 1]; tile[f * 33 + io + 1] = (v > 0.f) ? v : expm1f(v);
        v = s.z / dent[io + 2]; tile[f * 33 + io + 2] = (v > 0.f) ? v : expm1f(v);
        v = s.w / dent[io + 3]; tile[f * 33 + io + 3] = (v > 0.f) ? v : expm1f(v);
    }
    __syncthreads();
    #pragma unroll
    for (int e = 0; e < 4; ++e) {
        const int row = (t >> 5) * 4 + e;
        const int fo = (t & 31) * 4;
        const float4 v = { tile[(fo + 0) * 33 + row], tile[(fo + 1) * 33 + row],
                           tile[(fo + 2) * 33 + row], tile[(fo + 3) * 33 + row] };
        *(float4*)(out + (size_t)(i0 + row) * FOUT + fo) = v;
    }
}

// ---------------------------------------------------------------------------
extern "C" void kernel_launch(void* const* d_in, const int* in_sizes, int n_in,
                              void* d_out, int out_size, void* d_ws, size_t ws_size,
                              hipStream_t stream) {
    const float* input = (const float*)d_in[0];
    const int*   adj   = (const int*)d_in[1];
    const float* Ww    = (const float*)d_in[2];
    const float* Wb    = (const float*)d_in[3];
    const float* aw    = (const float*)d_in[4];
    const float* ab    = (const float*)d_in[5];
    float* out = (float*)d_out;

    char* ws = (char*)d_ws;
    unsigned short* hT3 = (unsigned short*)ws;               // 2 MB
    float* s_buf = (float*)(ws + (size_t)FOUT * NN * 2);     // 32 KB
    float* t_buf = s_buf + NN;                               // 32 KB
    float* dpart = t_buf + NN;                               // NCH*32 KB
    float* numw = dpart + (size_t)NCH * NN;                  // NCH*4 MB

    gat_pass_a<<<dim3(NN / 64), 256, 0, stream>>>(input, Ww, Wb, aw, ab, hT3, s_buf, t_buf);
    gat_pass_b<<<dim3(NN / ROWS, NCH), 256, 0, stream>>>(adj, hT3, s_buf, t_buf, numw, dpart);
    gat_reduce<<<dim3(NN / 32), 256, 0, stream>>>(numw, dpart, out, NCH);
}

// Round 7
// 106.146 us; speedup vs baseline: 2.2701x; 1.0882x over previous
//
#include <hip/hip_runtime.h>
#include <hip/hip_bf16.h>
#include <cmath>

#define NN 8192
#define FIN 256
#define FOUT 128
#define ROWS 32
#define NCH 4
#define JC (NN / NCH)        // 2048 j per chunk
#define NWINC (JC / 64)      // 32 windows per chunk
#define NWIN 8               // windows per wave (NWINC / 4 waves)

typedef short short8 __attribute__((ext_vector_type(8)));
typedef float f32x16 __attribute__((ext_vector_type(16)));
typedef unsigned long long u64;

static __device__ __forceinline__ unsigned short f2bf(float f) {
    unsigned u = __float_as_uint(f);
    u += 0x7fffu + ((u >> 16) & 1u);
    return (unsigned short)(u >> 16);
}

// ---------------------------------------------------------------------------
// Pass A: h = input @ W^T + Wb (bf16 MFMA). Writes hT3 in EXACT MFMA A-frag
// order: hT3[tile][fg][ks][lane][e] = h[fg*32+(lane&31)][tile*64+ks*16+(lane>>5)*8+e]
// so pass_b frag loads are 64-lane-contiguous 1KB. Also s = h·a1, t = h·a2+ab.
// ---------------------------------------------------------------------------
__global__ __launch_bounds__(256, 2)
void gat_pass_a(const float* __restrict__ input, const float* __restrict__ W,
                const float* __restrict__ Wb, const float* __restrict__ aw,
                const float* __restrict__ ab, unsigned short* __restrict__ hT3,
                float* __restrict__ s_out, float* __restrict__ t_out) {
    const int tid = threadIdx.x;
    const int w = tid >> 6, l = tid & 63;
    const int l5 = l >> 5, l31 = l & 31;
    const int nt = w >> 1, mh = w & 1;
    const int bx = blockIdx.x;
    const int i = bx * 64 + nt * 32 + l31;

    f32x16 acc0 = {}; f32x16 acc1 = {};
    #pragma unroll
    for (int ks = 0; ks < FIN / 16; ++ks) {
        const int c0 = ks * 16 + l5 * 8;
        const float4 b0 = *(const float4*)(input + (size_t)i * FIN + c0);
        const float4 b1 = *(const float4*)(input + (size_t)i * FIN + c0 + 4);
        short8 bf;
        bf[0]=(short)f2bf(b0.x); bf[1]=(short)f2bf(b0.y); bf[2]=(short)f2bf(b0.z); bf[3]=(short)f2bf(b0.w);
        bf[4]=(short)f2bf(b1.x); bf[5]=(short)f2bf(b1.y); bf[6]=(short)f2bf(b1.z); bf[7]=(short)f2bf(b1.w);
        {
            const int kcol = l31 + 32 * (2 * mh + 0);
            const float4 a0 = *(const float4*)(W + (size_t)kcol * FIN + c0);
            const float4 a1 = *(const float4*)(W + (size_t)kcol * FIN + c0 + 4);
            short8 af;
            af[0]=(short)f2bf(a0.x); af[1]=(short)f2bf(a0.y); af[2]=(short)f2bf(a0.z); af[3]=(short)f2bf(a0.w);
            af[4]=(short)f2bf(a1.x); af[5]=(short)f2bf(a1.y); af[6]=(short)f2bf(a1.z); af[7]=(short)f2bf(a1.w);
            acc0 = __builtin_amdgcn_mfma_f32_32x32x16_bf16(af, bf, acc0, 0, 0, 0);
        }
        {
            const int kcol = l31 + 32 * (2 * mh + 1);
            const float4 a0 = *(const float4*)(W + (size_t)kcol * FIN + c0);
            const float4 a1 = *(const float4*)(W + (size_t)kcol * FIN + c0 + 4);
            short8 af;
            af[0]=(short)f2bf(a0.x); af[1]=(short)f2bf(a0.y); af[2]=(short)f2bf(a0.z); af[3]=(short)f2bf(a0.w);
            af[4]=(short)f2bf(a1.x); af[5]=(short)f2bf(a1.y); af[6]=(short)f2bf(a1.z); af[7]=(short)f2bf(a1.w);
            acc1 = __builtin_amdgcn_mfma_f32_32x32x16_bf16(af, bf, acc1, 0, 0, 0);
        }
    }
    __shared__ float sred[4][32];
    __shared__ float tred[4][32];
    float sacc = 0.f, tacc = 0.f;
    const int jloc = nt * 32 + l31;
    const int ksb = jloc >> 4;
    const int lane_j = 32 * ((jloc >> 3) & 1);
    const int e = jloc & 7;
    #pragma unroll
    for (int m = 0; m < 2; ++m) {
        #pragma unroll
        for (int r = 0; r < 16; ++r) {
            const int kcol = 32 * (2 * mh + m) + 4 * l5 + (r & 3) + 8 * (r >> 2);
            const float hv = (m ? acc1[r] : acc0[r]) + Wb[kcol];
            const int fg = kcol >> 5;
            const int lane = (kcol & 31) + lane_j;
            hT3[((((size_t)bx * 4 + fg) * 4 + ksb) * 64 + lane) * 8 + e] = f2bf(hv);
            sacc += hv * aw[kcol];
            tacc += hv * aw[FOUT + kcol];
        }
    }
    sacc += __shfl_xor(sacc, 32);
    tacc += __shfl_xor(tacc, 32);
    if (l < 32) { sred[w][l] = sacc; tred[w][l] = tacc; }
    __syncthreads();
    if (mh == 0 && l < 32) {
        s_out[i] = sred[w][l] + sred[w + 1][l];
        t_out[i] = tred[w][l] + tred[w + 1][l] + ab[0];
    }
}

// ---------------------------------------------------------------------------
// Pass B, two-phase. Phase 1: each wave streams its 8 adj rows in 8KB
// CONTIGUOUS bursts (8 x 1KB wave-coalesced int4 loads per row) -> ballot
// -> u64 mask words in padded LDS [32][33]. Phase 2 (after one sync):
// round-6 consumption loop (exp -> bf16 -> 32x32x16 MFMA, coalesced hT3
// frags), masks from LDS. Epilogue: cross-wave LDS reduce, coalesced writes.
// ---------------------------------------------------------------------------
__global__ __launch_bounds__(256, 4)
void gat_pass_b(const int* __restrict__ adj, const unsigned short* __restrict__ hT3,
                const float* __restrict__ s_in, const float* __restrict__ t_in,
                float* __restrict__ numw, float* __restrict__ dpart) {
    __shared__ float red[FOUT * ROWS];       // 16 KB
    __shared__ float denb[4][ROWS];          // 512 B
    __shared__ u64 mask[ROWS][33];           // 8.25 KB (padded: 2-way banks only)
    const int tid = threadIdx.x;
    const int wv = tid >> 6, l = tid & 63;
    const int l5 = l >> 5, l31 = l & 31;
    const int i0 = blockIdx.x * ROWS;
    const int chunk = blockIdx.y;
    const int jb = chunk * JC;
    const float si = s_in[i0 + l31];

    // ---------- phase 1: mask production (wave wv: rows wv*8 .. wv*8+7) ----
    // load q of a row: lane l covers cols q*256 + 4l .. +3  (1KB contiguous)
    const int* arow = adj + (size_t)(i0 + wv * 8) * NN + jb + l * 4;
    const int lq = (l & 31) >> 2;   // which load this lane's word comes from
    const int sh = 16 * (l & 3);    // which 16-bit slice of each ballot
    int4 Rc[8];
    #pragma unroll
    for (int q = 0; q < 8; ++q) Rc[q] = *(const int4*)(arow + q * 256);
    #pragma unroll
    for (int rr = 0; rr < 8; ++rr) {
        u64 myword = 0;
        #pragma unroll
        for (int q = 0; q < 8; ++q) {
            const int4 a = Rc[q];
            const u64 b0 = __ballot(a.x > 0);
            const u64 b1 = __ballot(a.y > 0);
            const u64 b2 = __ballot(a.z > 0);
            const u64 b3 = __ballot(a.w > 0);
            if (lq == q) {
                myword = ((b0 >> sh) & 0xFFFFull)
                       | (((b1 >> sh) & 0xFFFFull) << 16)
                       | (((b2 >> sh) & 0xFFFFull) << 32)
                       | (((b3 >> sh) & 0xFFFFull) << 48);
            }
        }
        if (rr < 7) {
            #pragma unroll
            for (int q = 0; q < 8; ++q)
                Rc[q] = *(const int4*)(arow + (size_t)(rr + 1) * NN + q * 256);
        }
        if (l < 32) mask[wv * 8 + rr][l] = myword;   // word l = window l of row
    }
    __syncthreads();

    // ---------- phase 2: consumption (wave wv: windows wv*8 .. wv*8+7) -----
    f32x16 acc0 = {}, acc1 = {}, acc2 = {}, acc3 = {};
    float dacc = 0.f;

    for (int w = 0; w < NWIN; ++w) {
        const int win = wv * NWIN + w;
        const u64 myw = mask[l31][win];
        const int jw = jb + win * 64;
        const int tile = jw >> 6;
        #pragma unroll
        for (int ks = 0; ks < 4; ++ks) {
            const int jsl = jw + ks * 16 + l5 * 8;
            const float4 t0 = *(const float4*)(t_in + jsl);
            const float4 t1 = *(const float4*)(t_in + jsl + 4);
            const u64 m = myw >> (ks * 4 + l5 * 2);
            short8 bf;
            float x, p;
            x = si + t0.x; x = fmaxf(x, 0.2f * x); p = __expf(x);
            p = ((m >> 0)  & 1ull) ? p : 0.f; dacc += p; bf[0] = (short)f2bf(p);
            x = si + t0.y; x = fmaxf(x, 0.2f * x); p = __expf(x);
            p = ((m >> 16) & 1ull) ? p : 0.f; dacc += p; bf[1] = (short)f2bf(p);
            x = si + t0.z; x = fmaxf(x, 0.2f * x); p = __expf(x);
            p = ((m >> 32) & 1ull) ? p : 0.f; dacc += p; bf[2] = (short)f2bf(p);
            x = si + t0.w; x = fmaxf(x, 0.2f * x); p = __expf(x);
            p = ((m >> 48) & 1ull) ? p : 0.f; dacc += p; bf[3] = (short)f2bf(p);
            x = si + t1.x; x = fmaxf(x, 0.2f * x); p = __expf(x);
            p = ((m >> 1)  & 1ull) ? p : 0.f; dacc += p; bf[4] = (short)f2bf(p);
            x = si + t1.y; x = fmaxf(x, 0.2f * x); p = __expf(x);
            p = ((m >> 17) & 1ull) ? p : 0.f; dacc += p; bf[5] = (short)f2bf(p);
            x = si + t1.z; x = fmaxf(x, 0.2f * x); p = __expf(x);
            p = ((m >> 33) & 1ull) ? p : 0.f; dacc += p; bf[6] = (short)f2bf(p);
            x = si + t1.w; x = fmaxf(x, 0.2f * x); p = __expf(x);
            p = ((m >> 49) & 1ull) ? p : 0.f; dacc += p; bf[7] = (short)f2bf(p);

            const unsigned short* hp =
                hT3 + (((size_t)tile * 4) * 4 + ks) * 512 + (size_t)l * 8;
            const short8 af0 = *(const short8*)(hp);
            const short8 af1 = *(const short8*)(hp + 2048);
            const short8 af2 = *(const short8*)(hp + 4096);
            const short8 af3 = *(const short8*)(hp + 6144);
            acc0 = __builtin_amdgcn_mfma_f32_32x32x16_bf16(af0, bf, acc0, 0, 0, 0);
            acc1 = __builtin_amdgcn_mfma_f32_32x32x16_bf16(af1, bf, acc1, 0, 0, 0);
            acc2 = __builtin_amdgcn_mfma_f32_32x32x16_bf16(af2, bf, acc2, 0, 0, 0);
            acc3 = __builtin_amdgcn_mfma_f32_32x32x16_bf16(af3, bf, acc3, 0, 0, 0);
        }
    }

    // ---------- epilogue: cross-wave reduction (j-split partials) ----------
    #pragma unroll
    for (int ph = 0; ph < 4; ++ph) {
        __syncthreads();
        if (wv == ph) {
            #pragma unroll
            for (int r = 0; r < 16; ++r) {
                const int fr = (r & 3) + 8 * (r >> 2) + 4 * l5;
                if (ph == 0) {
                    red[(fr     ) * ROWS + l31] = acc0[r];
                    red[(fr + 32) * ROWS + l31] = acc1[r];
                    red[(fr + 64) * ROWS + l31] = acc2[r];
                    red[(fr + 96) * ROWS + l31] = acc3[r];
                } else {
                    red[(fr     ) * ROWS + l31] += acc0[r];
                    red[(fr + 32) * ROWS + l31] += acc1[r];
                    red[(fr + 64) * ROWS + l31] += acc2[r];
                    red[(fr + 96) * ROWS + l31] += acc3[r];
                }
            }
        }
    }
    dacc += __shfl_xor(dacc, 32);
    if (l5 == 0) denb[wv][l31] = dacc;
    __syncthreads();

    float* nb = numw + (size_t)chunk * FOUT * NN;
    #pragma unroll
    for (int e = 0; e < 4; ++e) {
        const int f = e * 32 + (tid >> 3);
        const int io = (tid & 7) * 4;
        *(float4*)(nb + (size_t)f * NN + i0 + io) = *(const float4*)(red + f * ROWS + io);
    }
    if (tid < ROWS)
        dpart[(size_t)chunk * NN + i0 + tid] =
            denb[0][tid] + denb[1][tid] + denb[2][tid] + denb[3][tid];
}

// ---------------------------------------------------------------------------
// Pass C: out[i][f] = elu( sum_c numw[c][f][i] / sum_c dpart[c][i] )
// ---------------------------------------------------------------------------
__global__ __launch_bounds__(256)
void gat_reduce(const float* __restrict__ numw, const float* __restrict__ dpart,
                float* __restrict__ out, int nchunk) {
    __shared__ float tile[FOUT * 33];
    __shared__ float dent[32];
    const int t = threadIdx.x;
    const int i0 = blockIdx.x * 32;
    if (t < 32) {
        float d = 0.f;
        for (int c = 0; c < nchunk; ++c) d += dpart[(size_t)c * NN + i0 + t];
        dent[t] = d;
    }
    __syncthreads();
    #pragma unroll
    for (int e = 0; e < 4; ++e) {
        const int f = e * 32 + (t >> 3);
        const int io = (t & 7) * 4;
        float4 s = {0.f, 0.f, 0.f, 0.f};
        for (int c = 0; c < nchunk; ++c) {
            const float4 v = *(const float4*)(numw + ((size_t)c * FOUT + f) * NN + i0 + io);
            s.x += v.x; s.y += v.y; s.z += v.z; s.w += v.w;
        }
        float v;
        v = s.x / dent[io + 0]; tile[f * 33 + io + 0] = (v > 0.f) ? v : expm1f(v);
        v = s.y / dent[io + 1]; tile[f * 33 + io + 1] = (v > 0.f) ? v : expm1f(v);
        v = s.z / dent[io + 2]; tile[f * 33 + io + 2] = (v > 0.f) ? v : expm1f(v);
        v = s.w / dent[io + 3]; tile[f * 33 + io + 3] = (v > 0.f) ? v : expm1f(v);
    }
    __syncthreads();
    #pragma unroll
    for (int e = 0; e < 4; ++e) {
        const int row = (t >> 5) * 4 + e;
        const int fo = (t & 31) * 4;
        const float4 v = { tile[(fo + 0) * 33 + row], tile[(fo + 1) * 33 + row],
                           tile[(fo + 2) * 33 + row], tile[(fo + 3) * 33 + row] };
        *(float4*)(out + (size_t)(i0 + row) * FOUT + fo) = v;
    }
}

// ---------------------------------------------------------------------------
extern "C" void kernel_launch(void* const* d_in, const int* in_sizes, int n_in,
                              void* d_out, int out_size, void* d_ws, size_t ws_size,
                              hipStream_t stream) {
    const float* input = (const float*)d_in[0];
    const int*   adj   = (const int*)d_in[1];
    const float* Ww    = (const float*)d_in[2];
    const float* Wb    = (const float*)d_in[3];
    const float* aw    = (const float*)d_in[4];
    const float* ab    = (const float*)d_in[5];
    float* out = (float*)d_out;

    char* ws = (char*)d_ws;
    unsigned short* hT3 = (unsigned short*)ws;               // 2 MB
    float* s_buf = (float*)(ws + (size_t)FOUT * NN * 2);     // 32 KB
    float* t_buf = s_buf + NN;                               // 32 KB
    float* dpart = t_buf + NN;                               // NCH*32 KB
    float* numw = dpart + (size_t)NCH * NN;                  // NCH*4 MB

    gat_pass_a<<<dim3(NN / 64), 256, 0, stream>>>(input, Ww, Wb, aw, ab, hT3, s_buf, t_buf);
    gat_pass_b<<<dim3(NN / ROWS, NCH), 256, 0, stream>>>(adj, hT3, s_buf, t_buf, numw, dpart);
    gat_reduce<<<dim3(NN / 32), 256, 0, stream>>>(numw, dpart, out, NCH);
}